// Round 10
// baseline (724.225 us; speedup 1.0000x reference)
//
#include <hip/hip_runtime.h>

#define B   64
#define KK  4096
#define D   256
#define Q   8
#define H   4
#define DH  64
#define HQ  32
#define HM  512
#define NCH 8
#define CHK 512
#define EPS 1e-8f
#define LNE 1e-5f
#define SCALE 0.125f

typedef short bf16x8 __attribute__((ext_vector_type(8)));
typedef float f32x4 __attribute__((ext_vector_type(4)));

#define MFMA __builtin_amdgcn_mfma_f32_16x16x32_bf16

__device__ __forceinline__ float bf2f(unsigned short u) {
    unsigned int x = ((unsigned int)u) << 16;
    float f; __builtin_memcpy(&f, &x, 4); return f;
}
__device__ __forceinline__ unsigned short f2bf(float f) {
    unsigned int x; __builtin_memcpy(&x, &f, 4);
    unsigned int lsb = (x >> 16) & 1u;
    x += 0x7fffu + lsb;
    return (unsigned short)(x >> 16);
}

__device__ __forceinline__ void gload16(const void* g, void* l) {
    __builtin_amdgcn_global_load_lds(
        (const __attribute__((address_space(1))) unsigned int*)g,
        (__attribute__((address_space(3))) unsigned int*)l, 16, 0, 0);
}

// stage a [64 rows x 512B] bf16 tile into LDS, XOR-swizzled ((r&7)<<4), via
// global_load_lds with pre-swizzled source. 8 issues/wave, 2 rows per 1KB seg.
__device__ __forceinline__ void stage64x512B(const char* src, size_t row0,
                                             size_t stride, char* lds, int w, int l)
{
#pragma unroll
    for (int i = 0; i < 8; ++i) {
        const int seg = w * 8 + i;
        const int r = seg * 2 + (l >> 5);
        const int off = ((l & 31) * 16) ^ ((r & 7) << 4);
        gload16(src + (row0 + r) * stride + off, lds + seg * 1024);
    }
}

// ---------------- fused prep: weight transforms + slots init ----------------
__global__ __launch_bounds__(256) void k_prep(
    const float* __restrict__ Wk, const float* __restrict__ Wv,
    const float* __restrict__ lnw, const float* __restrict__ lnb,
    const float* __restrict__ gWih, const float* __restrict__ gWhh,
    const float* __restrict__ W1, const float* __restrict__ W2,
    const float* __restrict__ Wq, const float* __restrict__ s0,
    unsigned short* __restrict__ wpk, float* __restrict__ cs, float* __restrict__ b2v,
    unsigned short* __restrict__ Wihbf, unsigned short* __restrict__ Whhbf,
    unsigned short* __restrict__ W1T, unsigned short* __restrict__ W2T,
    float* __restrict__ slots, unsigned short* __restrict__ slots_bf)
{
    const int blk = blockIdx.x, t = threadIdx.x;
    if (blk < 256) {                      // wpk subtiles (B-frag packed W')
        const int ct = blk >> 3, kt = blk & 7;
#pragma unroll
        for (int e2 = 0; e2 < 2; ++e2) {
            const int i = t * 2 + e2;
            const int lane = i >> 3, e = i & 7;
            const int col = ct * 16 + (lane & 15);
            const int k = kt * 32 + (lane >> 4) * 8 + e;
            const float wv = lnw[k];
            const float v = (col < 256) ? wv * Wk[(size_t)k * 256 + col] * SCALE
                                        : wv * Wv[(size_t)k * 256 + (col - 256)];
            wpk[(size_t)blk * 512 + i] = f2bf(v);
        }
    } else if (blk < 258) {               // cs (colsum of W') and b2 (ln_in_b @ W)
        const int c = (blk - 256) * 256 + t;
        float s1 = 0.f, s2 = 0.f;
        for (int k = 0; k < 256; ++k) {
            const float wraw = (c < 256) ? Wk[(size_t)k * 256 + c] * SCALE
                                         : Wv[(size_t)k * 256 + (c - 256)];
            s1 += lnw[k] * wraw;
            s2 += lnb[k] * wraw;
        }
        cs[c] = s1; b2v[c] = s2;
    } else if (blk < 1026) {              // Wih cvt
        const int i = (blk - 258) * 256 + t;
        Wihbf[i] = f2bf(gWih[i]);
    } else if (blk < 1794) {              // Whh cvt
        const int i = (blk - 1026) * 256 + t;
        Whhbf[i] = f2bf(gWhh[i]);
    } else if (blk < 2306) {              // W1T [512][256]
        const int nn = blk - 1794;
        W1T[(size_t)nn * 256 + t] = f2bf(W1[(size_t)t * 512 + nn]);
    } else if (blk < 2562) {              // W2T [256][512]
        const int nn = blk - 2306;
        W2T[(size_t)nn * 512 + t]       = f2bf(W2[(size_t)t * 256 + nn]);
        W2T[(size_t)nn * 512 + 256 + t] = f2bf(W2[(size_t)(256 + t) * 256 + nn]);
    } else {                              // slots init (512 blocks)
        const int i = (blk - 2562) * 256 + t;
        const float v = s0[i];
        slots[i] = v; slots_bf[i] = f2bf(v);
    }
}

// ---------------- K1: K/V projection — stores DEFERRED out of phase loop ----
// Per-phase barrier now drains only staging (already landed); all 64 global
// stores issue back-to-back at kernel end with one drain.
__global__ __launch_bounds__(256) void k1_mfma(
    const float* __restrict__ inp, const unsigned short* __restrict__ wpk,
    const float* __restrict__ cs, const float* __restrict__ b2v,
    unsigned short* __restrict__ kpk, unsigned short* __restrict__ vpk)
{
    __shared__ char smem[32768];
    char* abase = smem;                 // A region; becomes B dbuf after hoist
    char* bb0 = smem;
    char* bb1 = smem + 16384;
    const int t = threadIdx.x, w = t >> 6, l = t & 63;
    const size_t row0 = (size_t)blockIdx.x * 64;
    const int b_blk = blockIdx.x >> 6;
    const int kbase = (blockIdx.x & 63) * 64;
    const int lg = l >> 4;

    auto stageB = [&](int n2, char* dst) {
#pragma unroll
        for (int i = 0; i < 4; ++i) {
            const int seg = w * 4 + i;
            gload16((const char*)wpk + (size_t)n2 * 16384 + seg * 1024 + l * 16,
                    dst + seg * 1024);
        }
    };

    float4 xv[16];
#pragma unroll
    for (int i = 0; i < 16; ++i)
        xv[i] = ((const float4*)(inp + (row0 + w * 16 + i) * D))[l];
    float rsA = 0.f, muA = 0.f;
#pragma unroll
    for (int i = 0; i < 16; ++i) {
        const int r = w * 16 + i;
        const float4 x = xv[i];
        float s  = x.x + x.y + x.z + x.w;
        float ss = x.x*x.x + x.y*x.y + x.z*x.z + x.w*x.w;
#pragma unroll
        for (int off = 32; off; off >>= 1) { s += __shfl_xor(s, off); ss += __shfl_xor(ss, off); }
        const float mu = s * (1.f / 256.f);
        const float rs = rsqrtf(ss * (1.f / 256.f) - mu * mu + LNE);
        if ((l & 15) == i) { rsA = rs; muA = rs * mu; }
        ushort4 pk;
        pk.x = f2bf(x.x); pk.y = f2bf(x.y); pk.z = f2bf(x.z); pk.w = f2bf(x.w);
        *(ushort4*)(abase + r * 512 + ((l * 8) ^ ((r & 7) << 4))) = pk;
    }

    const int arow = w * 16 + (l & 15);
    const char* ap = abase + arow * 512;
    const int asw = (l & 7) << 4;
    bf16x8 af[8];
#pragma unroll
    for (int kk = 0; kk < 8; ++kk)
        af[kk] = *(const bf16x8*)(ap + ((kk * 64 + lg * 16) ^ asw));
    float rsV[4], muV[4];
#pragma unroll
    for (int r = 0; r < 4; ++r) {
        rsV[r] = __shfl(rsA, lg * 4 + r);
        muV[r] = __shfl(muA, lg * 4 + r);
    }
    __syncthreads();
    stageB(0, bb0); stageB(1, bb1);
    __syncthreads();

    const f32x4 fz = {0.f, 0.f, 0.f, 0.f};
    ushort4 kres[8][2];                 // deferred results (static-indexed)
    ushort4 vres[8][2];
#pragma unroll
    for (int n2 = 0; n2 < 16; ++n2) {
        const char* bbase = (n2 & 1) ? bb1 : bb0;
        f32x4 acc[2] = {fz, fz};
        if (n2 < 8) {
            // K half: swapped operands -> C[d][k]
#pragma unroll
            for (int kk = 0; kk < 8; ++kk) {
                const bf16x8 b0 = *(const bf16x8*)(bbase + kk * 1024 + l * 16);
                const bf16x8 b1 = *(const bf16x8*)(bbase + 8192 + kk * 1024 + l * 16);
                acc[0] = MFMA(b0, af[kk], acc[0], 0, 0, 0);
                acc[1] = MFMA(b1, af[kk], acc[1], 0, 0, 0);
            }
#pragma unroll
            for (int nf = 0; nf < 2; ++nf) {
                const int d0 = n2 * 32 + nf * 16 + lg * 4;
                const float4 cs4 = *(const float4*)(cs + d0);
                const float4 bb4 = *(const float4*)(b2v + d0);
                ushort4 pk;
                pk.x = f2bf(rsA * acc[nf][0] - muA * cs4.x + bb4.x);
                pk.y = f2bf(rsA * acc[nf][1] - muA * cs4.y + bb4.y);
                pk.z = f2bf(rsA * acc[nf][2] - muA * cs4.z + bb4.z);
                pk.w = f2bf(rsA * acc[nf][3] - muA * cs4.w + bb4.w);
                kres[n2][nf] = pk;
            }
        } else {
            // V half: normal orientation -> C[k][d]
#pragma unroll
            for (int kk = 0; kk < 8; ++kk) {
                const bf16x8 b0 = *(const bf16x8*)(bbase + kk * 1024 + l * 16);
                const bf16x8 b1 = *(const bf16x8*)(bbase + 8192 + kk * 1024 + l * 16);
                acc[0] = MFMA(af[kk], b0, acc[0], 0, 0, 0);
                acc[1] = MFMA(af[kk], b1, acc[1], 0, 0, 0);
            }
#pragma unroll
            for (int nf = 0; nf < 2; ++nf) {
                const int c = n2 * 32 + nf * 16 + (l & 15);
                const float csc = cs[c], b2c = b2v[c];
                ushort4 pk;
                pk.x = f2bf(rsV[0] * acc[nf][0] - muV[0] * csc + b2c);
                pk.y = f2bf(rsV[1] * acc[nf][1] - muV[1] * csc + b2c);
                pk.z = f2bf(rsV[2] * acc[nf][2] - muV[2] * csc + b2c);
                pk.w = f2bf(rsV[3] * acc[nf][3] - muV[3] * csc + b2c);
                vres[n2 - 8][nf] = pk;
            }
        }
        if (n2 < 15) __syncthreads();   // stage(n2+1) landed; buf reads done
        if (n2 < 14) stageB(n2 + 2, (n2 & 1) ? bb1 : bb0);
    }

    // ---- deferred store dump: fully pipelined, single drain at kernel end
    const int kt16 = (kbase >> 4) + w;
    const int klane = ((l & 15) + ((lg >> 1) << 5)) * 8 + (lg & 1) * 4;  // + nf*2<<4*8
#pragma unroll
    for (int n2 = 0; n2 < 8; ++n2) {
#pragma unroll
        for (int nf = 0; nf < 2; ++nf) {
            unsigned short* kp = kpk
                + ((((size_t)b_blk * 256 + kt16) * 8 + n2) * 512)
                + ((l & 15) + ((nf * 2 + (lg >> 1)) << 4)) * 8 + (lg & 1) * 4;
            *(ushort4*)kp = kres[n2][nf];
        }
    }
    const int kt32 = (kbase >> 5) + (w >> 1);
#pragma unroll
    for (int n2 = 0; n2 < 8; ++n2) {
#pragma unroll
        for (int nf = 0; nf < 2; ++nf) {
            const int dt16 = n2 * 2 + nf;
            unsigned short* vp = vpk
                + ((((size_t)b_blk * 128 + kt32) * 16 + dt16) * 512)
                + ((l & 15) + (((w & 1) * 2 + (lg >> 1)) << 4)) * 8 + (lg & 1) * 4;
            *(ushort4*)vp = vres[n2][nf];
        }
    }
    (void)klane;
}

// ---------------- K2: LN(slots) + q projection ----------------
__global__ __launch_bounds__(256) void k2_qproj(
    const float* __restrict__ slots, const float* __restrict__ Wq,
    const float* __restrict__ lnw, const float* __restrict__ lnb, float* __restrict__ qbuf)
{
    const int row = blockIdx.x, t = threadIdx.x;
    __shared__ float sn[256];
    __shared__ float red[8];
    const float x = slots[(size_t)row * D + t];
    float mu, rs;
    {
        float s = x, ss = x * x;
#pragma unroll
        for (int off = 32; off; off >>= 1) { s += __shfl_xor(s, off); ss += __shfl_xor(ss, off); }
        if ((t & 63) == 0) { red[t >> 6] = s; red[4 + (t >> 6)] = ss; }
        __syncthreads();
        const float S  = red[0] + red[1] + red[2] + red[3];
        const float SS = red[4] + red[5] + red[6] + red[7];
        mu = S * (1.f / 256.f);
        rs = rsqrtf(SS * (1.f / 256.f) - mu * mu + LNE);
    }
    sn[t] = (x - mu) * rs * lnw[t] + lnb[t];
    __syncthreads();
    float acc = 0.f;
    for (int d = 0; d < 256; ++d) acc = fmaf(sn[d], Wq[(size_t)d * 256 + t], acc);
    qbuf[(size_t)row * D + t] = acc;
}

// ---------------- fused attention (R8/R9 structure) ------------
__global__ __launch_bounds__(256) void k_attn(
    const unsigned short* __restrict__ kpk, const unsigned short* __restrict__ vpk,
    const float* __restrict__ qbuf, float* __restrict__ updp,
    float* __restrict__ denp, float* __restrict__ pbuf, int write_p)
{
    __shared__ unsigned short ksm[64 * 256];
    __shared__ unsigned short vsm[64 * 256];
    __shared__ unsigned short psm[2048];
    __shared__ float dred[4][32];
    const int t = threadIdx.x, w = t >> 6, l = t & 63;
    const int b = blockIdx.x >> 3, chunk = blockIdx.x & 7;
    const int k0g = chunk * CHK;
    const int n = l & 15, lg = l >> 4;

    auto stage_ks = [&](int tile) {
        const char* src = (const char*)kpk
            + (((size_t)b * 256 + chunk * 32 + tile * 4) * 8) * 1024 + l * 16;
#pragma unroll
        for (int i = 0; i < 8; ++i) {
            const int seg = w * 8 + i;
            gload16(src + seg * 1024, (char*)ksm + seg * 1024);
        }
    };
    auto stage_vs = [&](int tile) {
        const char* src = (const char*)vpk
            + (((size_t)b * 128 + chunk * 16 + tile * 2) * 16) * 1024 + l * 16;
#pragma unroll
        for (int i = 0; i < 8; ++i) {
            const int seg = w * 8 + i;
            gload16(src + seg * 1024, (char*)vsm + seg * 1024);
        }
    };
    stage_ks(0); stage_vs(0);

    bf16x8 qf[2][2];
#pragma unroll
    for (int p = 0; p < 2; ++p) {
        const int h = p * 2 + (n >> 3);
        const float* qb = qbuf + ((size_t)b * Q + (n & 7)) * D;
#pragma unroll
        for (int j = 0; j < 2; ++j) {
            const int dbase = (h * 2 + j) * 32 + lg * 8;
            short tmp[8];
#pragma unroll
            for (int e = 0; e < 8; ++e) tmp[e] = (short)f2bf(qb[dbase + e]);
            __builtin_memcpy(&qf[p][j], tmp, 16);
        }
    }
    const bf16x8 ZV = {0,0,0,0,0,0,0,0};
    const f32x4 fz = {0.f,0.f,0.f,0.f};
    f32x4 pv[2][4];
#pragma unroll
    for (int mt = 0; mt < 2; ++mt)
#pragma unroll
        for (int nf = 0; nf < 4; ++nf) pv[mt][nf] = fz;
    float den0 = 0.f, den1 = 0.f;

    for (int tile = 0; tile < 8; ++tile) {
        __syncthreads();
        f32x4 lac[2] = {fz, fz};
#pragma unroll
        for (int kk = 0; kk < 8; ++kk) {
            const bf16x8 kf = *(const bf16x8*)((char*)ksm + (w * 8 + kk) * 1024 + l * 16);
            const int p = kk >> 2;
            const bool on = (((kk & 3) >> 1) == (n >> 3));
            const bf16x8 bq = on ? qf[p][kk & 1] : ZV;
            if (p == 0) lac[0] = MFMA(kf, bq, lac[0], 0, 0, 0);
            else        lac[1] = MFMA(kf, bq, lac[1], 0, 0, 0);
        }
#pragma unroll
        for (int reg = 0; reg < 4; ++reg) {
            const float e0 = __expf(lac[0][reg]);
            const float e1 = __expf(lac[1][reg]);
            float se = e0 + e1;
#pragma unroll
            for (int off = 8; off; off >>= 1) se += __shfl_xor(se, off);
            const float inv = 1.f / se;
            lac[0][reg] = e0 * inv; lac[1][reg] = e1 * inv;
            den0 += lac[0][reg];    den1 += lac[1][reg];
        }
        char* pb = (char*)psm;
        const int kb = w * 16 + lg * 4;
        {
            ushort4 p0, p1;
            p0.x = f2bf(lac[0][0]); p0.y = f2bf(lac[0][1]); p0.z = f2bf(lac[0][2]); p0.w = f2bf(lac[0][3]);
            p1.x = f2bf(lac[1][0]); p1.y = f2bf(lac[1][1]); p1.z = f2bf(lac[1][2]); p1.w = f2bf(lac[1][3]);
            *(ushort4*)(pb + n * 128 + ((kb * 2) ^ ((n & 7) << 4))) = p0;
            *(ushort4*)(pb + (16 + n) * 128 + ((kb * 2) ^ ((n & 7) << 4))) = p1;
        }
        if (write_p) {
            float* pp = pbuf + ((size_t)b * KK + k0g + tile * 64 + kb) * HQ;
#pragma unroll
            for (int reg = 0; reg < 4; ++reg) {
                pp[(size_t)reg * HQ + n] = lac[0][reg];
                pp[(size_t)reg * HQ + 16 + n] = lac[1][reg];
            }
        }
        __syncthreads();
        if (tile < 7) stage_ks(tile + 1);
#pragma unroll
        for (int kkp = 0; kkp < 2; ++kkp) {
            const int koff = kkp * 64 + lg * 16;
            const bf16x8 a0 = *(const bf16x8*)(pb + n * 128 + (koff ^ ((n & 7) << 4)));
            const bf16x8 a1 = *(const bf16x8*)(pb + (16 + n) * 128 + (koff ^ ((n & 7) << 4)));
#pragma unroll
            for (int nf = 0; nf < 4; ++nf) {
                const bf16x8 bv = *(const bf16x8*)((char*)vsm + (kkp * 16 + w * 4 + nf) * 1024 + l * 16);
                pv[0][nf] = MFMA(a0, bv, pv[0][nf], 0, 0, 0);
                pv[1][nf] = MFMA(a1, bv, pv[1][nf], 0, 0, 0);
            }
        }
        __syncthreads();
        if (tile < 7) stage_vs(tile + 1);
    }

    den0 += __shfl_xor(den0, 16); den0 += __shfl_xor(den0, 32);
    den1 += __shfl_xor(den1, 16); den1 += __shfl_xor(den1, 32);
    if (l < 16) { dred[w][l] = den0; dred[w][16 + l] = den1; }
    __syncthreads();
    if (t < 32)
        denp[((size_t)b * NCH + chunk) * HQ + t] =
            dred[0][t] + dred[1][t] + dred[2][t] + dred[3][t];

    if ((lg >> 1) == (w & 1)) {
        const int mt = w >> 1;
#pragma unroll
        for (int nf = 0; nf < 4; ++nf) {
#pragma unroll
            for (int reg = 0; reg < 4; ++reg) {
                const int q = (lg & 1) * 4 + reg;
                updp[(((size_t)b * NCH + chunk) * Q + q) * D + w * 64 + nf * 16 + n] = pv[mt][nf][reg];
            }
        }
    }
}

// ---------------- reduce partials -> upd_bf (renormalized) ------------------
__global__ __launch_bounds__(256) void k_reduce(
    const float* __restrict__ updp, const float* __restrict__ denp,
    unsigned short* __restrict__ updbf)
{
    const int row = blockIdx.x, t = threadIdx.x;
    const int b = row >> 3, q = row & 7, h = t >> 6;
    float ds = 0.f, us = 0.f;
#pragma unroll
    for (int c = 0; c < NCH; ++c) {
        ds += denp[((size_t)b * NCH + c) * HQ + h * Q + q];
        us += updp[(((size_t)b * NCH + c) * Q + q) * D + t];
    }
    updbf[(size_t)row * D + t] = f2bf(us / (ds + (float)KK * EPS));
}

// ---------------- GRU gemm: gg[512][1536] = [u|h] @ [Wih;Whh]^T -------------
__global__ __launch_bounds__(256) void k_gru(
    const unsigned short* __restrict__ updbf, const unsigned short* __restrict__ slotsbf,
    const unsigned short* __restrict__ Wihbf, const unsigned short* __restrict__ Whhbf,
    float* __restrict__ gg)
{
    __shared__ unsigned short As[64 * 256];
    __shared__ unsigned short Bs[64 * 256];
    const int t = threadIdx.x, w = t >> 6, l = t & 63;
    const int rb = blockIdx.x / 24, nb = blockIdx.x % 24;
    const unsigned short* Asrc = (nb < 12) ? updbf : slotsbf;
    stage64x512B((const char*)Asrc, (size_t)rb * 64, 512, (char*)As, w, l);
    if (nb < 12) stage64x512B((const char*)Wihbf, (size_t)nb * 64, 512, (char*)Bs, w, l);
    else         stage64x512B((const char*)Whhbf, (size_t)(nb - 12) * 64, 512, (char*)Bs, w, l);
    __syncthreads();
    const int arow = w * 16 + (l & 15);
    const int asw = (l & 7) << 4;
    bf16x8 af[8];
#pragma unroll
    for (int kk = 0; kk < 8; ++kk)
        af[kk] = *(const bf16x8*)((char*)As + arow * 512 + ((kk * 64 + (l >> 4) * 16) ^ asw));
    const f32x4 fz = {0.f,0.f,0.f,0.f};
    f32x4 acc[4] = {fz, fz, fz, fz};
#pragma unroll
    for (int kk = 0; kk < 8; ++kk) {
        const int koff = kk * 64 + (l >> 4) * 16;
#pragma unroll
        for (int nf = 0; nf < 4; ++nf) {
            const int brow = nf * 16 + (l & 15);
            const bf16x8 bf_ = *(const bf16x8*)((char*)Bs + brow * 512 + (koff ^ ((brow & 7) << 4)));
            acc[nf] = MFMA(af[kk], bf_, acc[nf], 0, 0, 0);
        }
    }
    const int colbase = (nb < 12) ? nb * 64 : 768 + (nb - 12) * 64;
#pragma unroll
    for (int nf = 0; nf < 4; ++nf) {
        const int col = colbase + nf * 16 + (l & 15);
#pragma unroll
        for (int reg = 0; reg < 4; ++reg) {
            const size_t row = (size_t)rb * 64 + w * 16 + (l >> 4) * 4 + reg;
            gg[row * 1536 + col] = acc[nf][reg];
        }
    }
}

// ---------------- gates + LN(mlp) ----------------
__global__ __launch_bounds__(256) void k_gates(
    const float* __restrict__ gg, const float* __restrict__ slots,
    const float* __restrict__ bih, const float* __restrict__ bhh,
    const float* __restrict__ lnw, const float* __restrict__ lnb,
    float* __restrict__ snew, unsigned short* __restrict__ mbf)
{
    const int row = blockIdx.x, t = threadIdx.x;
    __shared__ float red[8];
    const float* g = gg + (size_t)row * 1536;
    const float i_r = g[t]        + bih[t];
    const float i_z = g[256 + t]  + bih[256 + t];
    const float i_n = g[512 + t]  + bih[512 + t];
    const float h_r = g[768 + t]  + bhh[t];
    const float h_z = g[1024 + t] + bhh[256 + t];
    const float h_n = g[1280 + t] + bhh[512 + t];
    const float r = 1.f / (1.f + __expf(-(i_r + h_r)));
    const float z = 1.f / (1.f + __expf(-(i_z + h_z)));
    const float nn = tanhf(i_n + r * h_n);
    const float h0 = slots[(size_t)row * D + t];
    const float sn = (1.f - z) * nn + z * h0;
    snew[(size_t)row * D + t] = sn;
    float mu, rs;
    {
        float s = sn, ss = sn * sn;
#pragma unroll
        for (int off = 32; off; off >>= 1) { s += __shfl_xor(s, off); ss += __shfl_xor(ss, off); }
        if ((t & 63) == 0) { red[t >> 6] = s; red[4 + (t >> 6)] = ss; }
        __syncthreads();
        const float S  = red[0] + red[1] + red[2] + red[3];
        const float SS = red[4] + red[5] + red[6] + red[7];
        mu = S * (1.f / 256.f);
        rs = rsqrtf(SS * (1.f / 256.f) - mu * mu + LNE);
    }
    mbf[(size_t)row * D + t] = f2bf((sn - mu) * rs * lnw[t] + lnb[t]);
}

// ---------------- MLP gemm 1: hid = relu(m @ W1 + b1) -----------------------
__global__ __launch_bounds__(256) void k_mlp1(
    const unsigned short* __restrict__ mbf, const unsigned short* __restrict__ W1T,
    const float* __restrict__ b1, unsigned short* __restrict__ hidbf)
{
    __shared__ unsigned short As[64 * 256];
    __shared__ unsigned short Bs[64 * 256];
    const int t = threadIdx.x, w = t >> 6, l = t & 63;
    const int rb = blockIdx.x >> 3, nb = blockIdx.x & 7;
    stage64x512B((const char*)mbf, (size_t)rb * 64, 512, (char*)As, w, l);
    stage64x512B((const char*)W1T, (size_t)nb * 64, 512, (char*)Bs, w, l);
    __syncthreads();
    const int arow = w * 16 + (l & 15);
    const int asw = (l & 7) << 4;
    bf16x8 af[8];
#pragma unroll
    for (int kk = 0; kk < 8; ++kk)
        af[kk] = *(const bf16x8*)((char*)As + arow * 512 + ((kk * 64 + (l >> 4) * 16) ^ asw));
    const f32x4 fz = {0.f,0.f,0.f,0.f};
    f32x4 acc[4] = {fz, fz, fz, fz};
#pragma unroll
    for (int kk = 0; kk < 8; ++kk) {
        const int koff = kk * 64 + (l >> 4) * 16;
#pragma unroll
        for (int nf = 0; nf < 4; ++nf) {
            const int brow = nf * 16 + (l & 15);
            const bf16x8 bf_ = *(const bf16x8*)((char*)Bs + brow * 512 + (koff ^ ((brow & 7) << 4)));
            acc[nf] = MFMA(af[kk], bf_, acc[nf], 0, 0, 0);
        }
    }
#pragma unroll
    for (int nf = 0; nf < 4; ++nf) {
        const int col = nb * 64 + nf * 16 + (l & 15);
        const float bb = b1[col];
#pragma unroll
        for (int reg = 0; reg < 4; ++reg) {
            const size_t row = (size_t)rb * 64 + w * 16 + (l >> 4) * 4 + reg;
            hidbf[row * HM + col] = f2bf(fmaxf(acc[nf][reg] + bb, 0.f));
        }
    }
}

// ---------------- MLP gemm 2 + residual -> slots ----------------------------
__global__ __launch_bounds__(256) void k_mlp2(
    const unsigned short* __restrict__ hidbf, const unsigned short* __restrict__ W2T,
    const float* __restrict__ b2, const float* __restrict__ snew,
    float* __restrict__ slots, unsigned short* __restrict__ slotsbf,
    float* __restrict__ outp)
{
    __shared__ unsigned short As[64 * 256];
    __shared__ unsigned short Bs[64 * 256];
    const int t = threadIdx.x, w = t >> 6, l = t & 63;
    const int rb = blockIdx.x >> 2, nb = blockIdx.x & 3;
    const f32x4 fz = {0.f,0.f,0.f,0.f};
    f32x4 acc[4] = {fz, fz, fz, fz};
    for (int c = 0; c < 2; ++c) {
        stage64x512B((const char*)hidbf + c * 512, (size_t)rb * 64, 1024, (char*)As, w, l);
        stage64x512B((const char*)W2T + c * 512, (size_t)nb * 64, 1024, (char*)Bs, w, l);
        __syncthreads();
        const int arow = w * 16 + (l & 15);
        const int asw = (l & 7) << 4;
        bf16x8 af[8];
#pragma unroll
        for (int kk = 0; kk < 8; ++kk)
            af[kk] = *(const bf16x8*)((char*)As + arow * 512 + ((kk * 64 + (l >> 4) * 16) ^ asw));
#pragma unroll
        for (int kk = 0; kk < 8; ++kk) {
            const int koff = kk * 64 + (l >> 4) * 16;
#pragma unroll
            for (int nf = 0; nf < 4; ++nf) {
                const int brow = nf * 16 + (l & 15);
                const bf16x8 bf_ = *(const bf16x8*)((char*)Bs + brow * 512 + (koff ^ ((brow & 7) << 4)));
                acc[nf] = MFMA(af[kk], bf_, acc[nf], 0, 0, 0);
            }
        }
        __syncthreads();
    }
#pragma unroll
    for (int nf = 0; nf < 4; ++nf) {
        const int col = nb * 64 + nf * 16 + (l & 15);
        const float bb = b2[col];
#pragma unroll
        for (int reg = 0; reg < 4; ++reg) {
            const size_t row = (size_t)rb * 64 + w * 16 + (l >> 4) * 4 + reg;
            const float v = snew[row * D + col] + acc[nf][reg] + bb;
            slots[row * D + col] = v;
            slotsbf[row * D + col] = f2bf(v);
            if (outp) outp[row * D + col] = v;
        }
    }
}

// ---------------- attn output (invden computed inline) ----------------------
__global__ __launch_bounds__(256) void k7_attnout(
    const float* __restrict__ pbuf, const float* __restrict__ denp, float* __restrict__ out2)
{
    const int blk = blockIdx.x;
    const int b = blk >> 4;
    const int kk0 = (blk & 15) * 256;
    __shared__ float ps[256][33];
    __shared__ float inv[32];
    const int t = threadIdx.x;
    const float* pp = pbuf + ((size_t)b * KK + kk0) * HQ;
    for (int i = 0; i < 32; ++i) {
        const int idx = i * 256 + t;
        ps[idx >> 5][idx & 31] = pp[idx];
    }
    if (t < 32) {
        float s = 0.f;
#pragma unroll
        for (int c = 0; c < NCH; ++c) s += denp[((size_t)b * NCH + c) * HQ + t];
        inv[t] = 1.f / (s + (float)KK * EPS);
    }
    __syncthreads();
    float* o = out2 + (size_t)b * Q * KK + kk0 + t;
#pragma unroll
    for (int q = 0; q < 8; ++q) {
        float v = 0.f;
#pragma unroll
        for (int hh = 0; hh < 4; ++hh)
            v += (ps[t][hh * 8 + q] + EPS) * inv[hh * 8 + q];
        o[(size_t)q * KK] = v * 0.25f;
    }
}

extern "C" void kernel_launch(void* const* d_in, const int* in_sizes, int n_in,
                              void* d_out, int out_size, void* d_ws, size_t ws_size,
                              hipStream_t stream)
{
    const float* inputs  = (const float*)d_in[0];
    const float* slots0  = (const float*)d_in[1];
    const float* Wq      = (const float*)d_in[2];
    const float* Wk      = (const float*)d_in[3];
    const float* Wv      = (const float*)d_in[4];
    const float* ln_in_w = (const float*)d_in[5];
    const float* ln_in_b = (const float*)d_in[6];
    const float* ln_s_w  = (const float*)d_in[7];
    const float* ln_s_b  = (const float*)d_in[8];
    const float* ln_m_w  = (const float*)d_in[9];
    const float* ln_m_b  = (const float*)d_in[10];
    const float* gWih    = (const float*)d_in[11];
    const float* gWhh    = (const float*)d_in[12];
    const float* gbih    = (const float*)d_in[13];
    const float* gbhh    = (const float*)d_in[14];
    const float* W1      = (const float*)d_in[15];
    const float* b1      = (const float*)d_in[16];
    const float* W2      = (const float*)d_in[17];
    const float* b2      = (const float*)d_in[18];

    char* p = (char*)d_ws;
    unsigned short* kpk   = (unsigned short*)p; p += (size_t)B * KK * D * 2;
    unsigned short* vpk   = (unsigned short*)p; p += (size_t)B * KK * D * 2;
    float* pbuf   = (float*)p; p += (size_t)B * KK * HQ * 4;
    float* updp   = (float*)p; p += (size_t)B * NCH * Q * D * 4;   // gg aliases
    float* denp   = (float*)p; p += (size_t)B * NCH * HQ * 4;
    float* qbuf   = (float*)p; p += (size_t)B * Q * D * 4;
    float* slots  = (float*)p; p += (size_t)B * Q * D * 4;
    float* snew   = (float*)p; p += (size_t)B * Q * D * 4;
    unsigned short* slots_bf = (unsigned short*)p; p += (size_t)B * Q * D * 2;
    unsigned short* upd_bf   = (unsigned short*)p; p += (size_t)B * Q * D * 2;
    unsigned short* mbf      = (unsigned short*)p; p += (size_t)B * Q * D * 2;
    unsigned short* hidbf    = (unsigned short*)p; p += (size_t)B * Q * HM * 2;
    unsigned short* wpk   = (unsigned short*)p; p += (size_t)512 * 256 * 2;
    float* csv    = (float*)p; p += 512 * 4;
    float* b2vv   = (float*)p; p += 512 * 4;
    unsigned short* Wihbf = (unsigned short*)p; p += (size_t)768 * 256 * 2;
    unsigned short* Whhbf = (unsigned short*)p; p += (size_t)768 * 256 * 2;
    unsigned short* W1T   = (unsigned short*)p; p += (size_t)HM * 256 * 2;
    unsigned short* W2T   = (unsigned short*)p; p += (size_t)256 * HM * 2;
    float* gg = updp;   // alias: gg[512][1536] (3.1MB) < updp (4.2MB); lifetimes disjoint

    k_prep<<<3074, 256, 0, stream>>>(Wk, Wv, ln_in_w, ln_in_b, gWih, gWhh, W1, W2, Wq, slots0,
                                     wpk, csv, b2vv, Wihbf, Whhbf, W1T, W2T, slots, slots_bf);
    k1_mfma<<<(B * KK) / 64, 256, 0, stream>>>(inputs, wpk, csv, b2vv, kpk, vpk);
    k2_qproj<<<B * Q, 256, 0, stream>>>(slots, Wq, ln_s_w, ln_s_b, qbuf);
    for (int it = 0; it < 3; ++it) {
        k_attn<<<B * NCH, 256, 0, stream>>>(kpk, vpk, qbuf, updp, denp, pbuf, (it == 2) ? 1 : 0);
        k_reduce<<<B * Q, 256, 0, stream>>>(updp, denp, upd_bf);
        k_gru<<<8 * 24, 256, 0, stream>>>(upd_bf, slots_bf, Wihbf, Whhbf, gg);
        k_gates<<<B * Q, 256, 0, stream>>>(gg, slots, gbih, gbhh, ln_m_w, ln_m_b, snew, mbf);
        k_mlp1<<<8 * 8, 256, 0, stream>>>(mbf, W1T, b1, hidbf);
        k_mlp2<<<8 * 4, 256, 0, stream>>>(hidbf, W2T, b2, snew, slots, slots_bf,
                                          (it == 2) ? (float*)d_out : (float*)nullptr);
        if (it < 2)
            k2_qproj<<<B * Q, 256, 0, stream>>>(slots, Wq, ln_s_w, ln_s_b, qbuf);
    }
    k7_attnout<<<B * (KK / 256), 256, 0, stream>>>(pbuf, denp, (float*)d_out + (size_t)B * Q * D);
}

// Round 11
// 485.491 us; speedup vs baseline: 1.4917x; 1.4917x over previous
//
#include <hip/hip_runtime.h>

#define B   64
#define KK  4096
#define D   256
#define Q   8
#define H   4
#define DH  64
#define HQ  32
#define HM  512
#define NCH 8
#define CHK 512
#define EPS 1e-8f
#define LNE 1e-5f
#define SCALE 0.125f

typedef short bf16x8 __attribute__((ext_vector_type(8)));
typedef float f32x4 __attribute__((ext_vector_type(4)));

#define MFMA __builtin_amdgcn_mfma_f32_16x16x32_bf16

__device__ __forceinline__ float bf2f(unsigned short u) {
    unsigned int x = ((unsigned int)u) << 16;
    float f; __builtin_memcpy(&f, &x, 4); return f;
}
__device__ __forceinline__ unsigned short f2bf(float f) {
    unsigned int x; __builtin_memcpy(&x, &f, 4);
    unsigned int lsb = (x >> 16) & 1u;
    x += 0x7fffu + lsb;
    return (unsigned short)(x >> 16);
}

__device__ __forceinline__ void gload16(const void* g, void* l) {
    __builtin_amdgcn_global_load_lds(
        (const __attribute__((address_space(1))) unsigned int*)g,
        (__attribute__((address_space(3))) unsigned int*)l, 16, 0, 0);
}

// stage a [64 rows x 512B] bf16 tile into LDS, XOR-swizzled ((r&7)<<4)
__device__ __forceinline__ void stage64x512B(const char* src, size_t row0,
                                             size_t stride, char* lds, int w, int l)
{
#pragma unroll
    for (int i = 0; i < 8; ++i) {
        const int seg = w * 8 + i;
        const int r = seg * 2 + (l >> 5);
        const int off = ((l & 31) * 16) ^ ((r & 7) << 4);
        gload16(src + (row0 + r) * stride + off, lds + seg * 1024);
    }
}

// ---------------- fused prep: weight transforms + slots init ----------------
__global__ __launch_bounds__(256) void k_prep(
    const float* __restrict__ Wk, const float* __restrict__ Wv,
    const float* __restrict__ lnw, const float* __restrict__ lnb,
    const float* __restrict__ gWih, const float* __restrict__ gWhh,
    const float* __restrict__ W1, const float* __restrict__ W2,
    const float* __restrict__ Wq, const float* __restrict__ s0,
    unsigned short* __restrict__ wpk, float* __restrict__ cs, float* __restrict__ b2v,
    unsigned short* __restrict__ Wihbf, unsigned short* __restrict__ Whhbf,
    unsigned short* __restrict__ W1T, unsigned short* __restrict__ W2T,
    float* __restrict__ slots, unsigned short* __restrict__ slots_bf)
{
    const int blk = blockIdx.x, t = threadIdx.x;
    if (blk < 256) {                      // wpk subtiles (B-frag packed W')
        const int ct = blk >> 3, kt = blk & 7;
#pragma unroll
        for (int e2 = 0; e2 < 2; ++e2) {
            const int i = t * 2 + e2;
            const int lane = i >> 3, e = i & 7;
            const int col = ct * 16 + (lane & 15);
            const int k = kt * 32 + (lane >> 4) * 8 + e;
            const float wv = lnw[k];
            const float v = (col < 256) ? wv * Wk[(size_t)k * 256 + col] * SCALE
                                        : wv * Wv[(size_t)k * 256 + (col - 256)];
            wpk[(size_t)blk * 512 + i] = f2bf(v);
        }
    } else if (blk < 258) {               // cs (colsum of W') and b2 (ln_in_b @ W)
        const int c = (blk - 256) * 256 + t;
        float s1 = 0.f, s2 = 0.f;
        for (int k = 0; k < 256; ++k) {
            const float wraw = (c < 256) ? Wk[(size_t)k * 256 + c] * SCALE
                                         : Wv[(size_t)k * 256 + (c - 256)];
            s1 += lnw[k] * wraw;
            s2 += lnb[k] * wraw;
        }
        cs[c] = s1; b2v[c] = s2;
    } else if (blk < 1026) {              // Wih cvt
        const int i = (blk - 258) * 256 + t;
        Wihbf[i] = f2bf(gWih[i]);
    } else if (blk < 1794) {              // Whh cvt
        const int i = (blk - 1026) * 256 + t;
        Whhbf[i] = f2bf(gWhh[i]);
    } else if (blk < 2306) {              // W1T [512][256]
        const int nn = blk - 1794;
        W1T[(size_t)nn * 256 + t] = f2bf(W1[(size_t)t * 512 + nn]);
    } else if (blk < 2562) {              // W2T [256][512]
        const int nn = blk - 2306;
        W2T[(size_t)nn * 512 + t]       = f2bf(W2[(size_t)t * 256 + nn]);
        W2T[(size_t)nn * 512 + 256 + t] = f2bf(W2[(size_t)(256 + t) * 256 + nn]);
    } else {                              // slots init (512 blocks)
        const int i = (blk - 2562) * 256 + t;
        const float v = s0[i];
        slots[i] = v; slots_bf[i] = f2bf(v);
    }
}

// ---------------- K1: K/V projection — counted-vmcnt barriers (T4) ----------
// Per-phase: exactly 2 stores (vm) + 4 stage loads (vm). s_waitcnt vmcnt(2)
// ensures stage(n2+1) landed while the 2 just-issued stores stay in flight.
// cs/b2v staged in LDS so epilogue reads don't perturb the vm count.
__global__ __launch_bounds__(256) void k1_mfma(
    const float* __restrict__ inp, const unsigned short* __restrict__ wpk,
    const float* __restrict__ cs, const float* __restrict__ b2v,
    unsigned short* __restrict__ kpk, unsigned short* __restrict__ vpk)
{
    __shared__ char smem[36864];
    char* abase = smem;                 // A region; becomes B dbuf after hoist
    char* bb0 = smem;
    char* bb1 = smem + 16384;
    float* csm = (float*)(smem + 32768);   // 512 f32
    float* b2m = (float*)(smem + 34816);   // 512 f32
    const int t = threadIdx.x, w = t >> 6, l = t & 63;
    const size_t row0 = (size_t)blockIdx.x * 64;
    const int b_blk = blockIdx.x >> 6;
    const int kbase = (blockIdx.x & 63) * 64;
    const int lg = l >> 4;

    auto stageB = [&](int n2, char* dst) {
#pragma unroll
        for (int i = 0; i < 4; ++i) {
            const int seg = w * 4 + i;
            gload16((const char*)wpk + (size_t)n2 * 16384 + seg * 1024 + l * 16,
                    dst + seg * 1024);
        }
    };

    // cs/b2v -> LDS (one time; consumed loads, so drained before staging)
    csm[t] = cs[t];       csm[256 + t] = cs[256 + t];
    b2m[t] = b2v[t];      b2m[256 + t] = b2v[256 + t];

    float4 xv[16];
#pragma unroll
    for (int i = 0; i < 16; ++i)
        xv[i] = ((const float4*)(inp + (row0 + w * 16 + i) * D))[l];
    float rsA = 0.f, muA = 0.f;
#pragma unroll
    for (int i = 0; i < 16; ++i) {
        const int r = w * 16 + i;
        const float4 x = xv[i];
        float s  = x.x + x.y + x.z + x.w;
        float ss = x.x*x.x + x.y*x.y + x.z*x.z + x.w*x.w;
#pragma unroll
        for (int off = 32; off; off >>= 1) { s += __shfl_xor(s, off); ss += __shfl_xor(ss, off); }
        const float mu = s * (1.f / 256.f);
        const float rs = rsqrtf(ss * (1.f / 256.f) - mu * mu + LNE);
        if ((l & 15) == i) { rsA = rs; muA = rs * mu; }
        ushort4 pk;
        pk.x = f2bf(x.x); pk.y = f2bf(x.y); pk.z = f2bf(x.z); pk.w = f2bf(x.w);
        *(ushort4*)(abase + r * 512 + ((l * 8) ^ ((r & 7) << 4))) = pk;
    }

    const int arow = w * 16 + (l & 15);
    const char* ap = abase + arow * 512;
    const int asw = (l & 7) << 4;
    bf16x8 af[8];
#pragma unroll
    for (int kk = 0; kk < 8; ++kk)
        af[kk] = *(const bf16x8*)(ap + ((kk * 64 + lg * 16) ^ asw));
    float rsV[4], muV[4];
#pragma unroll
    for (int r = 0; r < 4; ++r) {
        rsV[r] = __shfl(rsA, lg * 4 + r);
        muV[r] = __shfl(muA, lg * 4 + r);
    }
    // A-hoist reads + csm writes complete; then B staging may overwrite A region
    asm volatile("s_waitcnt lgkmcnt(0)" ::: "memory");
    __builtin_amdgcn_s_barrier();
    __builtin_amdgcn_sched_barrier(0);
    stageB(0, bb0); stageB(1, bb1);
    asm volatile("s_waitcnt vmcnt(4) lgkmcnt(0)" ::: "memory");  // stage(0) landed
    __builtin_amdgcn_s_barrier();
    __builtin_amdgcn_sched_barrier(0);

    const f32x4 fz = {0.f, 0.f, 0.f, 0.f};
    for (int n2 = 0; n2 < 16; ++n2) {
        const char* bbase = (n2 & 1) ? bb1 : bb0;
        f32x4 acc[2] = {fz, fz};
        if (n2 < 8) {
            // K half: swapped operands -> C[d][k]
#pragma unroll
            for (int kk = 0; kk < 8; ++kk) {
                const bf16x8 b0 = *(const bf16x8*)(bbase + kk * 1024 + l * 16);
                const bf16x8 b1 = *(const bf16x8*)(bbase + 8192 + kk * 1024 + l * 16);
                acc[0] = MFMA(b0, af[kk], acc[0], 0, 0, 0);
                acc[1] = MFMA(b1, af[kk], acc[1], 0, 0, 0);
            }
            const int kt16 = (kbase >> 4) + w;
#pragma unroll
            for (int nf = 0; nf < 2; ++nf) {
                const int d0 = n2 * 32 + nf * 16 + lg * 4;
                const float4 cs4 = *(const float4*)(csm + d0);
                const float4 bb4 = *(const float4*)(b2m + d0);
                unsigned short* kp = kpk
                    + ((((size_t)b_blk * 256 + kt16) * 8 + n2) * 512)
                    + ((l & 15) + ((nf * 2 + (lg >> 1)) << 4)) * 8 + (lg & 1) * 4;
                ushort4 pk;
                pk.x = f2bf(rsA * acc[nf][0] - muA * cs4.x + bb4.x);
                pk.y = f2bf(rsA * acc[nf][1] - muA * cs4.y + bb4.y);
                pk.z = f2bf(rsA * acc[nf][2] - muA * cs4.z + bb4.z);
                pk.w = f2bf(rsA * acc[nf][3] - muA * cs4.w + bb4.w);
                *(ushort4*)kp = pk;
            }
        } else {
            // V half: normal orientation -> C[k][d]
#pragma unroll
            for (int kk = 0; kk < 8; ++kk) {
                const bf16x8 b0 = *(const bf16x8*)(bbase + kk * 1024 + l * 16);
                const bf16x8 b1 = *(const bf16x8*)(bbase + 8192 + kk * 1024 + l * 16);
                acc[0] = MFMA(af[kk], b0, acc[0], 0, 0, 0);
                acc[1] = MFMA(af[kk], b1, acc[1], 0, 0, 0);
            }
            const int kt32 = (kbase >> 5) + (w >> 1);
#pragma unroll
            for (int nf = 0; nf < 2; ++nf) {
                const int c = n2 * 32 + nf * 16 + (l & 15);
                const float csc = csm[c], b2c = b2m[c];
                const int dt16 = (n2 - 8) * 2 + nf;
                unsigned short* vp = vpk
                    + ((((size_t)b_blk * 128 + kt32) * 16 + dt16) * 512)
                    + ((l & 15) + (((w & 1) * 2 + (lg >> 1)) << 4)) * 8 + (lg & 1) * 4;
                ushort4 pk;
                pk.x = f2bf(rsV[0] * acc[nf][0] - muV[0] * csc + b2c);
                pk.y = f2bf(rsV[1] * acc[nf][1] - muV[1] * csc + b2c);
                pk.z = f2bf(rsV[2] * acc[nf][2] - muV[2] * csc + b2c);
                pk.w = f2bf(rsV[3] * acc[nf][3] - muV[3] * csc + b2c);
                *(ushort4*)vp = pk;
            }
        }
        if (n2 < 15) {
            // counted wait: allow this phase's 2 stores to stay in flight;
            // everything older (incl. stage(n2+1)) is drained.
            asm volatile("s_waitcnt vmcnt(2) lgkmcnt(0)" ::: "memory");
            __builtin_amdgcn_s_barrier();
            __builtin_amdgcn_sched_barrier(0);
            if (n2 < 14) stageB(n2 + 2, (n2 & 1) ? bb1 : bb0);
        }
    }
}

// ---------------- K2: LN(slots) + q projection ----------------
__global__ __launch_bounds__(256) void k2_qproj(
    const float* __restrict__ slots, const float* __restrict__ Wq,
    const float* __restrict__ lnw, const float* __restrict__ lnb, float* __restrict__ qbuf)
{
    const int row = blockIdx.x, t = threadIdx.x;
    __shared__ float sn[256];
    __shared__ float red[8];
    const float x = slots[(size_t)row * D + t];
    float mu, rs;
    {
        float s = x, ss = x * x;
#pragma unroll
        for (int off = 32; off; off >>= 1) { s += __shfl_xor(s, off); ss += __shfl_xor(ss, off); }
        if ((t & 63) == 0) { red[t >> 6] = s; red[4 + (t >> 6)] = ss; }
        __syncthreads();
        const float S  = red[0] + red[1] + red[2] + red[3];
        const float SS = red[4] + red[5] + red[6] + red[7];
        mu = S * (1.f / 256.f);
        rs = rsqrtf(SS * (1.f / 256.f) - mu * mu + LNE);
    }
    sn[t] = (x - mu) * rs * lnw[t] + lnb[t];
    __syncthreads();
    float acc = 0.f;
    for (int d = 0; d < 256; ++d) acc = fmaf(sn[d], Wq[(size_t)d * 256 + t], acc);
    qbuf[(size_t)row * D + t] = acc;
}

// ---------------- fused attention (R8/R9 structure) ------------
__global__ __launch_bounds__(256) void k_attn(
    const unsigned short* __restrict__ kpk, const unsigned short* __restrict__ vpk,
    const float* __restrict__ qbuf, float* __restrict__ updp,
    float* __restrict__ denp, float* __restrict__ pbuf, int write_p)
{
    __shared__ unsigned short ksm[64 * 256];
    __shared__ unsigned short vsm[64 * 256];
    __shared__ unsigned short psm[2048];
    __shared__ float dred[4][32];
    const int t = threadIdx.x, w = t >> 6, l = t & 63;
    const int b = blockIdx.x >> 3, chunk = blockIdx.x & 7;
    const int k0g = chunk * CHK;
    const int n = l & 15, lg = l >> 4;

    auto stage_ks = [&](int tile) {
        const char* src = (const char*)kpk
            + (((size_t)b * 256 + chunk * 32 + tile * 4) * 8) * 1024 + l * 16;
#pragma unroll
        for (int i = 0; i < 8; ++i) {
            const int seg = w * 8 + i;
            gload16(src + seg * 1024, (char*)ksm + seg * 1024);
        }
    };
    auto stage_vs = [&](int tile) {
        const char* src = (const char*)vpk
            + (((size_t)b * 128 + chunk * 16 + tile * 2) * 16) * 1024 + l * 16;
#pragma unroll
        for (int i = 0; i < 8; ++i) {
            const int seg = w * 8 + i;
            gload16(src + seg * 1024, (char*)vsm + seg * 1024);
        }
    };
    stage_ks(0); stage_vs(0);

    bf16x8 qf[2][2];
#pragma unroll
    for (int p = 0; p < 2; ++p) {
        const int h = p * 2 + (n >> 3);
        const float* qb = qbuf + ((size_t)b * Q + (n & 7)) * D;
#pragma unroll
        for (int j = 0; j < 2; ++j) {
            const int dbase = (h * 2 + j) * 32 + lg * 8;
            short tmp[8];
#pragma unroll
            for (int e = 0; e < 8; ++e) tmp[e] = (short)f2bf(qb[dbase + e]);
            __builtin_memcpy(&qf[p][j], tmp, 16);
        }
    }
    const bf16x8 ZV = {0,0,0,0,0,0,0,0};
    const f32x4 fz = {0.f,0.f,0.f,0.f};
    f32x4 pv[2][4];
#pragma unroll
    for (int mt = 0; mt < 2; ++mt)
#pragma unroll
        for (int nf = 0; nf < 4; ++nf) pv[mt][nf] = fz;
    float den0 = 0.f, den1 = 0.f;

    for (int tile = 0; tile < 8; ++tile) {
        __syncthreads();
        f32x4 lac[2] = {fz, fz};
#pragma unroll
        for (int kk = 0; kk < 8; ++kk) {
            const bf16x8 kf = *(const bf16x8*)((char*)ksm + (w * 8 + kk) * 1024 + l * 16);
            const int p = kk >> 2;
            const bool on = (((kk & 3) >> 1) == (n >> 3));
            const bf16x8 bq = on ? qf[p][kk & 1] : ZV;
            if (p == 0) lac[0] = MFMA(kf, bq, lac[0], 0, 0, 0);
            else        lac[1] = MFMA(kf, bq, lac[1], 0, 0, 0);
        }
#pragma unroll
        for (int reg = 0; reg < 4; ++reg) {
            const float e0 = __expf(lac[0][reg]);
            const float e1 = __expf(lac[1][reg]);
            float se = e0 + e1;
#pragma unroll
            for (int off = 8; off; off >>= 1) se += __shfl_xor(se, off);
            const float inv = 1.f / se;
            lac[0][reg] = e0 * inv; lac[1][reg] = e1 * inv;
            den0 += lac[0][reg];    den1 += lac[1][reg];
        }
        char* pb = (char*)psm;
        const int kb = w * 16 + lg * 4;
        {
            ushort4 p0, p1;
            p0.x = f2bf(lac[0][0]); p0.y = f2bf(lac[0][1]); p0.z = f2bf(lac[0][2]); p0.w = f2bf(lac[0][3]);
            p1.x = f2bf(lac[1][0]); p1.y = f2bf(lac[1][1]); p1.z = f2bf(lac[1][2]); p1.w = f2bf(lac[1][3]);
            *(ushort4*)(pb + n * 128 + ((kb * 2) ^ ((n & 7) << 4))) = p0;
            *(ushort4*)(pb + (16 + n) * 128 + ((kb * 2) ^ ((n & 7) << 4))) = p1;
        }
        if (write_p) {
            float* pp = pbuf + ((size_t)b * KK + k0g + tile * 64 + kb) * HQ;
#pragma unroll
            for (int reg = 0; reg < 4; ++reg) {
                pp[(size_t)reg * HQ + n] = lac[0][reg];
                pp[(size_t)reg * HQ + 16 + n] = lac[1][reg];
            }
        }
        __syncthreads();
        if (tile < 7) stage_ks(tile + 1);
#pragma unroll
        for (int kkp = 0; kkp < 2; ++kkp) {
            const int koff = kkp * 64 + lg * 16;
            const bf16x8 a0 = *(const bf16x8*)(pb + n * 128 + (koff ^ ((n & 7) << 4)));
            const bf16x8 a1 = *(const bf16x8*)(pb + (16 + n) * 128 + (koff ^ ((n & 7) << 4)));
#pragma unroll
            for (int nf = 0; nf < 4; ++nf) {
                const bf16x8 bv = *(const bf16x8*)((char*)vsm + (kkp * 16 + w * 4 + nf) * 1024 + l * 16);
                pv[0][nf] = MFMA(a0, bv, pv[0][nf], 0, 0, 0);
                pv[1][nf] = MFMA(a1, bv, pv[1][nf], 0, 0, 0);
            }
        }
        __syncthreads();
        if (tile < 7) stage_vs(tile + 1);
    }

    den0 += __shfl_xor(den0, 16); den0 += __shfl_xor(den0, 32);
    den1 += __shfl_xor(den1, 16); den1 += __shfl_xor(den1, 32);
    if (l < 16) { dred[w][l] = den0; dred[w][16 + l] = den1; }
    __syncthreads();
    if (t < 32)
        denp[((size_t)b * NCH + chunk) * HQ + t] =
            dred[0][t] + dred[1][t] + dred[2][t] + dred[3][t];

    if ((lg >> 1) == (w & 1)) {
        const int mt = w >> 1;
#pragma unroll
        for (int nf = 0; nf < 4; ++nf) {
#pragma unroll
            for (int reg = 0; reg < 4; ++reg) {
                const int q = (lg & 1) * 4 + reg;
                updp[(((size_t)b * NCH + chunk) * Q + q) * D + w * 64 + nf * 16 + n] = pv[mt][nf][reg];
            }
        }
    }
}

// ---------------- reduce partials -> upd_bf (renormalized) ------------------
__global__ __launch_bounds__(256) void k_reduce(
    const float* __restrict__ updp, const float* __restrict__ denp,
    unsigned short* __restrict__ updbf)
{
    const int row = blockIdx.x, t = threadIdx.x;
    const int b = row >> 3, q = row & 7, h = t >> 6;
    float ds = 0.f, us = 0.f;
#pragma unroll
    for (int c = 0; c < NCH; ++c) {
        ds += denp[((size_t)b * NCH + c) * HQ + h * Q + q];
        us += updp[(((size_t)b * NCH + c) * Q + q) * D + t];
    }
    updbf[(size_t)row * D + t] = f2bf(us / (ds + (float)KK * EPS));
}

// ---------------- GRU gemm: gg[512][1536] = [u|h] @ [Wih;Whh]^T -------------
__global__ __launch_bounds__(256) void k_gru(
    const unsigned short* __restrict__ updbf, const unsigned short* __restrict__ slotsbf,
    const unsigned short* __restrict__ Wihbf, const unsigned short* __restrict__ Whhbf,
    float* __restrict__ gg)
{
    __shared__ unsigned short As[64 * 256];
    __shared__ unsigned short Bs[64 * 256];
    const int t = threadIdx.x, w = t >> 6, l = t & 63;
    const int rb = blockIdx.x / 24, nb = blockIdx.x % 24;
    const unsigned short* Asrc = (nb < 12) ? updbf : slotsbf;
    stage64x512B((const char*)Asrc, (size_t)rb * 64, 512, (char*)As, w, l);
    if (nb < 12) stage64x512B((const char*)Wihbf, (size_t)nb * 64, 512, (char*)Bs, w, l);
    else         stage64x512B((const char*)Whhbf, (size_t)(nb - 12) * 64, 512, (char*)Bs, w, l);
    __syncthreads();
    const int arow = w * 16 + (l & 15);
    const int asw = (l & 7) << 4;
    bf16x8 af[8];
#pragma unroll
    for (int kk = 0; kk < 8; ++kk)
        af[kk] = *(const bf16x8*)((char*)As + arow * 512 + ((kk * 64 + (l >> 4) * 16) ^ asw));
    const f32x4 fz = {0.f,0.f,0.f,0.f};
    f32x4 acc[4] = {fz, fz, fz, fz};
#pragma unroll
    for (int kk = 0; kk < 8; ++kk) {
        const int koff = kk * 64 + (l >> 4) * 16;
#pragma unroll
        for (int nf = 0; nf < 4; ++nf) {
            const int brow = nf * 16 + (l & 15);
            const bf16x8 bf_ = *(const bf16x8*)((char*)Bs + brow * 512 + (koff ^ ((brow & 7) << 4)));
            acc[nf] = MFMA(af[kk], bf_, acc[nf], 0, 0, 0);
        }
    }
    const int colbase = (nb < 12) ? nb * 64 : 768 + (nb - 12) * 64;
#pragma unroll
    for (int nf = 0; nf < 4; ++nf) {
        const int col = colbase + nf * 16 + (l & 15);
#pragma unroll
        for (int reg = 0; reg < 4; ++reg) {
            const size_t row = (size_t)rb * 64 + w * 16 + (l >> 4) * 4 + reg;
            gg[row * 1536 + col] = acc[nf][reg];
        }
    }
}

// ---------------- gates + LN(mlp) ----------------
__global__ __launch_bounds__(256) void k_gates(
    const float* __restrict__ gg, const float* __restrict__ slots,
    const float* __restrict__ bih, const float* __restrict__ bhh,
    const float* __restrict__ lnw, const float* __restrict__ lnb,
    float* __restrict__ snew, unsigned short* __restrict__ mbf)
{
    const int row = blockIdx.x, t = threadIdx.x;
    __shared__ float red[8];
    const float* g = gg + (size_t)row * 1536;
    const float i_r = g[t]        + bih[t];
    const float i_z = g[256 + t]  + bih[256 + t];
    const float i_n = g[512 + t]  + bih[512 + t];
    const float h_r = g[768 + t]  + bhh[t];
    const float h_z = g[1024 + t] + bhh[256 + t];
    const float h_n = g[1280 + t] + bhh[512 + t];
    const float r = 1.f / (1.f + __expf(-(i_r + h_r)));
    const float z = 1.f / (1.f + __expf(-(i_z + h_z)));
    const float nn = tanhf(i_n + r * h_n);
    const float h0 = slots[(size_t)row * D + t];
    const float sn = (1.f - z) * nn + z * h0;
    snew[(size_t)row * D + t] = sn;
    float mu, rs;
    {
        float s = sn, ss = sn * sn;
#pragma unroll
        for (int off = 32; off; off >>= 1) { s += __shfl_xor(s, off); ss += __shfl_xor(ss, off); }
        if ((t & 63) == 0) { red[t >> 6] = s; red[4 + (t >> 6)] = ss; }
        __syncthreads();
        const float S  = red[0] + red[1] + red[2] + red[3];
        const float SS = red[4] + red[5] + red[6] + red[7];
        mu = S * (1.f / 256.f);
        rs = rsqrtf(SS * (1.f / 256.f) - mu * mu + LNE);
    }
    mbf[(size_t)row * D + t] = f2bf((sn - mu) * rs * lnw[t] + lnb[t]);
}

// ---------------- MLP gemm 1: hid = relu(m @ W1 + b1) -----------------------
__global__ __launch_bounds__(256) void k_mlp1(
    const unsigned short* __restrict__ mbf, const unsigned short* __restrict__ W1T,
    const float* __restrict__ b1, unsigned short* __restrict__ hidbf)
{
    __shared__ unsigned short As[64 * 256];
    __shared__ unsigned short Bs[64 * 256];
    const int t = threadIdx.x, w = t >> 6, l = t & 63;
    const int rb = blockIdx.x >> 3, nb = blockIdx.x & 7;
    stage64x512B((const char*)mbf, (size_t)rb * 64, 512, (char*)As, w, l);
    stage64x512B((const char*)W1T, (size_t)nb * 64, 512, (char*)Bs, w, l);
    __syncthreads();
    const int arow = w * 16 + (l & 15);
    const int asw = (l & 7) << 4;
    bf16x8 af[8];
#pragma unroll
    for (int kk = 0; kk < 8; ++kk)
        af[kk] = *(const bf16x8*)((char*)As + arow * 512 + ((kk * 64 + (l >> 4) * 16) ^ asw));
    const f32x4 fz = {0.f,0.f,0.f,0.f};
    f32x4 acc[4] = {fz, fz, fz, fz};
#pragma unroll
    for (int kk = 0; kk < 8; ++kk) {
        const int koff = kk * 64 + (l >> 4) * 16;
#pragma unroll
        for (int nf = 0; nf < 4; ++nf) {
            const int brow = nf * 16 + (l & 15);
            const bf16x8 bf_ = *(const bf16x8*)((char*)Bs + brow * 512 + (koff ^ ((brow & 7) << 4)));
            acc[nf] = MFMA(af[kk], bf_, acc[nf], 0, 0, 0);
        }
    }
#pragma unroll
    for (int nf = 0; nf < 4; ++nf) {
        const int col = nb * 64 + nf * 16 + (l & 15);
        const float bb = b1[col];
#pragma unroll
        for (int reg = 0; reg < 4; ++reg) {
            const size_t row = (size_t)rb * 64 + w * 16 + (l >> 4) * 4 + reg;
            hidbf[row * HM + col] = f2bf(fmaxf(acc[nf][reg] + bb, 0.f));
        }
    }
}

// ---------------- MLP gemm 2 + residual -> slots ----------------------------
__global__ __launch_bounds__(256) void k_mlp2(
    const unsigned short* __restrict__ hidbf, const unsigned short* __restrict__ W2T,
    const float* __restrict__ b2, const float* __restrict__ snew,
    float* __restrict__ slots, unsigned short* __restrict__ slotsbf,
    float* __restrict__ outp)
{
    __shared__ unsigned short As[64 * 256];
    __shared__ unsigned short Bs[64 * 256];
    const int t = threadIdx.x, w = t >> 6, l = t & 63;
    const int rb = blockIdx.x >> 2, nb = blockIdx.x & 3;
    const f32x4 fz = {0.f,0.f,0.f,0.f};
    f32x4 acc[4] = {fz, fz, fz, fz};
    for (int c = 0; c < 2; ++c) {
        stage64x512B((const char*)hidbf + c * 512, (size_t)rb * 64, 1024, (char*)As, w, l);
        stage64x512B((const char*)W2T + c * 512, (size_t)nb * 64, 1024, (char*)Bs, w, l);
        __syncthreads();
        const int arow = w * 16 + (l & 15);
        const int asw = (l & 7) << 4;
        bf16x8 af[8];
#pragma unroll
        for (int kk = 0; kk < 8; ++kk)
            af[kk] = *(const bf16x8*)((char*)As + arow * 512 + ((kk * 64 + (l >> 4) * 16) ^ asw));
#pragma unroll
        for (int kk = 0; kk < 8; ++kk) {
            const int koff = kk * 64 + (l >> 4) * 16;
#pragma unroll
            for (int nf = 0; nf < 4; ++nf) {
                const int brow = nf * 16 + (l & 15);
                const bf16x8 bf_ = *(const bf16x8*)((char*)Bs + brow * 512 + (koff ^ ((brow & 7) << 4)));
                acc[nf] = MFMA(af[kk], bf_, acc[nf], 0, 0, 0);
            }
        }
        __syncthreads();
    }
#pragma unroll
    for (int nf = 0; nf < 4; ++nf) {
        const int col = nb * 64 + nf * 16 + (l & 15);
        const float bb = b2[col];
#pragma unroll
        for (int reg = 0; reg < 4; ++reg) {
            const size_t row = (size_t)rb * 64 + w * 16 + (l >> 4) * 4 + reg;
            const float v = snew[row * D + col] + acc[nf][reg] + bb;
            slots[row * D + col] = v;
            slotsbf[row * D + col] = f2bf(v);
            if (outp) outp[row * D + col] = v;
        }
    }
}

// ---------------- attn output (invden computed inline) ----------------------
__global__ __launch_bounds__(256) void k7_attnout(
    const float* __restrict__ pbuf, const float* __restrict__ denp, float* __restrict__ out2)
{
    const int blk = blockIdx.x;
    const int b = blk >> 4;
    const int kk0 = (blk & 15) * 256;
    __shared__ float ps[256][33];
    __shared__ float inv[32];
    const int t = threadIdx.x;
    const float* pp = pbuf + ((size_t)b * KK + kk0) * HQ;
    for (int i = 0; i < 32; ++i) {
        const int idx = i * 256 + t;
        ps[idx >> 5][idx & 31] = pp[idx];
    }
    if (t < 32) {
        float s = 0.f;
#pragma unroll
        for (int c = 0; c < NCH; ++c) s += denp[((size_t)b * NCH + c) * HQ + t];
        inv[t] = 1.f / (s + (float)KK * EPS);
    }
    __syncthreads();
    float* o = out2 + (size_t)b * Q * KK + kk0 + t;
#pragma unroll
    for (int q = 0; q < 8; ++q) {
        float v = 0.f;
#pragma unroll
        for (int hh = 0; hh < 4; ++hh)
            v += (ps[t][hh * 8 + q] + EPS) * inv[hh * 8 + q];
        o[(size_t)q * KK] = v * 0.25f;
    }
}

extern "C" void kernel_launch(void* const* d_in, const int* in_sizes, int n_in,
                              void* d_out, int out_size, void* d_ws, size_t ws_size,
                              hipStream_t stream)
{
    const float* inputs  = (const float*)d_in[0];
    const float* slots0  = (const float*)d_in[1];
    const float* Wq      = (const float*)d_in[2];
    const float* Wk      = (const float*)d_in[3];
    const float* Wv      = (const float*)d_in[4];
    const float* ln_in_w = (const float*)d_in[5];
    const float* ln_in_b = (const float*)d_in[6];
    const float* ln_s_w  = (const float*)d_in[7];
    const float* ln_s_b  = (const float*)d_in[8];
    const float* ln_m_w  = (const float*)d_in[9];
    const float* ln_m_b  = (const float*)d_in[10];
    const float* gWih    = (const float*)d_in[11];
    const float* gWhh    = (const float*)d_in[12];
    const float* gbih    = (const float*)d_in[13];
    const float* gbhh    = (const float*)d_in[14];
    const float* W1      = (const float*)d_in[15];
    const float* b1      = (const float*)d_in[16];
    const float* W2      = (const float*)d_in[17];
    const float* b2      = (const float*)d_in[18];

    char* p = (char*)d_ws;
    unsigned short* kpk   = (unsigned short*)p; p += (size_t)B * KK * D * 2;
    unsigned short* vpk   = (unsigned short*)p; p += (size_t)B * KK * D * 2;
    float* pbuf   = (float*)p; p += (size_t)B * KK * HQ * 4;
    float* updp   = (float*)p; p += (size_t)B * NCH * Q * D * 4;   // gg aliases
    float* denp   = (float*)p; p += (size_t)B * NCH * HQ * 4;
    float* qbuf   = (float*)p; p += (size_t)B * Q * D * 4;
    float* slots  = (float*)p; p += (size_t)B * Q * D * 4;
    float* snew   = (float*)p; p += (size_t)B * Q * D * 4;
    unsigned short* slots_bf = (unsigned short*)p; p += (size_t)B * Q * D * 2;
    unsigned short* upd_bf   = (unsigned short*)p; p += (size_t)B * Q * D * 2;
    unsigned short* mbf      = (unsigned short*)p; p += (size_t)B * Q * D * 2;
    unsigned short* hidbf    = (unsigned short*)p; p += (size_t)B * Q * HM * 2;
    unsigned short* wpk   = (unsigned short*)p; p += (size_t)512 * 256 * 2;
    float* csv    = (float*)p; p += 512 * 4;
    float* b2vv   = (float*)p; p += 512 * 4;
    unsigned short* Wihbf = (unsigned short*)p; p += (size_t)768 * 256 * 2;
    unsigned short* Whhbf = (unsigned short*)p; p += (size_t)768 * 256 * 2;
    unsigned short* W1T   = (unsigned short*)p; p += (size_t)HM * 256 * 2;
    unsigned short* W2T   = (unsigned short*)p; p += (size_t)256 * HM * 2;
    float* gg = updp;   // alias: gg[512][1536] (3.1MB) < updp (4.2MB); lifetimes disjoint

    k_prep<<<3074, 256, 0, stream>>>(Wk, Wv, ln_in_w, ln_in_b, gWih, gWhh, W1, W2, Wq, slots0,
                                     wpk, csv, b2vv, Wihbf, Whhbf, W1T, W2T, slots, slots_bf);
    k1_mfma<<<(B * KK) / 64, 256, 0, stream>>>(inputs, wpk, csv, b2vv, kpk, vpk);
    k2_qproj<<<B * Q, 256, 0, stream>>>(slots, Wq, ln_s_w, ln_s_b, qbuf);
    for (int it = 0; it < 3; ++it) {
        k_attn<<<B * NCH, 256, 0, stream>>>(kpk, vpk, qbuf, updp, denp, pbuf, (it == 2) ? 1 : 0);
        k_reduce<<<B * Q, 256, 0, stream>>>(updp, denp, upd_bf);
        k_gru<<<8 * 24, 256, 0, stream>>>(upd_bf, slots_bf, Wihbf, Whhbf, gg);
        k_gates<<<B * Q, 256, 0, stream>>>(gg, slots, gbih, gbhh, ln_m_w, ln_m_b, snew, mbf);
        k_mlp1<<<8 * 8, 256, 0, stream>>>(mbf, W1T, b1, hidbf);
        k_mlp2<<<8 * 4, 256, 0, stream>>>(hidbf, W2T, b2, snew, slots, slots_bf,
                                          (it == 2) ? (float*)d_out : (float*)nullptr);
        if (it < 2)
            k2_qproj<<<B * Q, 256, 0, stream>>>(slots, Wq, ln_s_w, ln_s_b, qbuf);
    }
    k7_attnout<<<B * (KK / 256), 256, 0, stream>>>(pbuf, denp, (float*)d_out + (size_t)B * Q * D);
}